// Round 4
// baseline (325.847 us; speedup 1.0000x reference)
//
#include <hip/hip_runtime.h>
#include <math.h>

#define B_  2
#define N_  384
#define C_  256
#define H_  4
#define D_  64
#define NBH (B_*H_)            // 8
#define TSZ (NBH*N_*D_)        // 196608 floats per projected tensor [bh][n][d]
#define ESZ (NBH*N_*N_)        // 1179648 elems per logit matrix
#define SCALE 0.125f           // D^-0.5

typedef _Float16 f16;
typedef f16  f16x8 __attribute__((ext_vector_type(8)));
typedef f16  f16x4 __attribute__((ext_vector_type(4)));
typedef float f32x4 __attribute__((ext_vector_type(4)));

// ---------------------------------------------------------------------------
// Kernel 1: projection. proj[t][bh][n][d], t in {a,b,c,v1,v2}, f32.
// ---------------------------------------------------------------------------
__global__ __launch_bounds__(256) void proj_kernel(const float* __restrict__ x,
                                                   const float* __restrict__ W,
                                                   float* __restrict__ proj) {
    __shared__ float Xs[32][68];
    __shared__ float Ws[32][68];
    const int tid = threadIdx.x;
    const int tx = tid & 15, ty = tid >> 4;
    const int m0 = blockIdx.x * 64;
    const int c0 = blockIdx.y * 64;
    const int t  = c0 >> 8;
    const int wbase = ((t >= 3) ? (t + 3) : t) * 256;

    float acc[4][4] = {{0.f}};
    for (int k0 = 0; k0 < 256; k0 += 32) {
        __syncthreads();
#pragma unroll
        for (int l = 0; l < 8; ++l) {
            const int idx = l * 256 + tid;
            const int mi = idx >> 5, kk = idx & 31;
            Xs[kk][mi] = x[(m0 + mi) * 256 + k0 + kk];
            const int rem = (c0 + mi) & 255;
            Ws[kk][mi] = W[(wbase + rem) * 256 + k0 + kk];
        }
        __syncthreads();
#pragma unroll
        for (int kk = 0; kk < 32; ++kk) {
            const float4 xf = *(const float4*)&Xs[kk][ty * 4];
            const float4 wf = *(const float4*)&Ws[kk][tx * 4];
            const float xa[4] = {xf.x, xf.y, xf.z, xf.w};
            const float wa[4] = {wf.x, wf.y, wf.z, wf.w};
#pragma unroll
            for (int q = 0; q < 4; ++q)
#pragma unroll
                for (int p = 0; p < 4; ++p)
                    acc[q][p] += xa[q] * wa[p];
        }
    }
#pragma unroll
    for (int q = 0; q < 4; ++q) {
        const int r = m0 + ty * 4 + q;
        const int b = r / N_;
        const int n = r - b * N_;
#pragma unroll
        for (int p = 0; p < 4; ++p) {
            const int rem = (c0 + tx * 4 + p) & 255;
            const int h = rem >> 6, d = rem & 63;
            proj[t * TSZ + ((b * H_ + h) * N_ + n) * D_ + d] = acc[q][p];
        }
    }
}

// ---------------------------------------------------------------------------
// Kernel 2: exp-logit matrices, f16.
//  q=0: eABt16[bh][j][i]   q=1: eCD16[bh][i][k]   q=2: eEF16[bh][j][k]
// ---------------------------------------------------------------------------
__global__ __launch_bounds__(256) void logits_kernel(const float* __restrict__ proj,
                                                     f16* __restrict__ eabt16,
                                                     f16* __restrict__ ecd16,
                                                     f16* __restrict__ eef16) {
    __shared__ float Xs[32][68];
    __shared__ float Ys[32][68];
    const int tid = threadIdx.x;
    const int tx = tid & 15, ty = tid >> 4;
    const int i0 = blockIdx.x * 64, j0 = blockIdx.y * 64;
    const int q  = blockIdx.z >> 3;
    const int bh = blockIdx.z & 7;
    const int xt = q;
    const int yt = (q == 2) ? 0 : (q + 1);
    const float* Xp = proj + xt * TSZ + bh * N_ * D_;
    const float* Yp = proj + yt * TSZ + bh * N_ * D_;

    float acc[4][4] = {{0.f}};
    for (int k0 = 0; k0 < 64; k0 += 32) {
        __syncthreads();
#pragma unroll
        for (int l = 0; l < 8; ++l) {
            const int idx = l * 256 + tid;
            const int mi = idx >> 5, kk = idx & 31;
            Xs[kk][mi] = Xp[(i0 + mi) * 64 + k0 + kk];
            Ys[kk][mi] = Yp[(j0 + mi) * 64 + k0 + kk];
        }
        __syncthreads();
#pragma unroll
        for (int kk = 0; kk < 32; ++kk) {
            const float4 xf = *(const float4*)&Xs[kk][ty * 4];
            const float4 yf = *(const float4*)&Ys[kk][tx * 4];
            const float xa[4] = {xf.x, xf.y, xf.z, xf.w};
            const float ya[4] = {yf.x, yf.y, yf.z, yf.w};
#pragma unroll
            for (int qq = 0; qq < 4; ++qq)
#pragma unroll
                for (int p = 0; p < 4; ++p)
                    acc[qq][p] += xa[qq] * ya[p];
        }
    }
#pragma unroll
    for (int qq = 0; qq < 4; ++qq)
#pragma unroll
        for (int p = 0; p < 4; ++p) {
            const float e = expf(acc[qq][p] * SCALE);
            const int ii = i0 + ty * 4 + qq;
            const int jj = j0 + tx * 4 + p;
            if (q == 0)      eabt16[(size_t)bh * N_ * N_ + jj * N_ + ii] = (f16)e;
            else if (q == 1) ecd16 [(size_t)bh * N_ * N_ + ii * N_ + jj] = (f16)e;
            else             eef16 [(size_t)bh * N_ * N_ + ii * N_ + jj] = (f16)e;
        }
}

// ---------------------------------------------------------------------------
// Kernel 2b: transpose v1/v2 to vt[t][bh][d][n] f16 (t=0: v1, t=1: v2).
// ---------------------------------------------------------------------------
__global__ __launch_bounds__(256) void vtrans_kernel(const float* __restrict__ proj,
                                                     f16* __restrict__ vt) {
    __shared__ f16 tile[64][65];
    const int tid = threadIdx.x;
    const int n0 = blockIdx.x * 64;
    const int bh = blockIdx.y;
    const int t  = blockIdx.z;
    const float* src = proj + (3 + t) * TSZ + ((size_t)bh * N_ + n0) * 64;
#pragma unroll
    for (int rep = 0; rep < 16; ++rep) {
        const int idx = rep * 256 + tid;
        const int r = idx >> 6, d = idx & 63;
        tile[d][r] = (f16)src[r * 64 + d];
    }
    __syncthreads();
#pragma unroll
    for (int rep = 0; rep < 16; ++rep) {
        const int idx = rep * 256 + tid;
        const int d = idx >> 6, c = idx & 63;
        vt[((size_t)(t * NBH + bh) * 64 + d) * N_ + n0 + c] = tile[d][c];
    }
}

// ---------------------------------------------------------------------------
// Kernel 3 (dominant): register-resident MFMA.
// Block = (i-tile 64, j-tile 64, bh, d-half). Each wave caches eCD A-frags
// (96 VGPR) + eEF B-frags (96 VGPR) for the whole block and owns 9 d-slices
// (slot s = w*9+t, d = dh*36+s; d==64 -> denominator, d>64 skipped).
// Per d: A rebuilt as cf*v2 (v_pk_mul), 192 MFMAs from registers, fold once,
// non-atomic store to per-j-tile partials numw6[jt][bh][i][68].
// One barrier per block.
// ---------------------------------------------------------------------------
__global__ __launch_bounds__(256, 1) void triplet_reg_kernel(
        const f16* __restrict__ eabt,    // [bh][j][i]
        const f16* __restrict__ ecdh,    // [bh][i][k]
        const f16* __restrict__ eefh,    // [bh][j][k]
        const f16* __restrict__ vt,      // [2][bh][d][n] (0:v1, 1:v2)
        float* __restrict__ numw6) {     // [jt][bh][i][68]
    __shared__ __align__(16) f16 v2s[36 * 384];    // 27648 B

    const int tid  = threadIdx.x;
    const int lane = tid & 63;
    const int w    = tid >> 6;
    const int quad = lane >> 4;
    const int lr   = lane & 15;
    const int i0 = blockIdx.x * 64;
    const int jt = blockIdx.y;
    const int j0 = jt * 64;
    const int bh = blockIdx.z >> 1;
    const int dh = blockIdx.z & 1;

    const f16* eabtb = eabt + (size_t)bh * N_ * N_;
    const f16* ecdb  = ecdh + (size_t)bh * N_ * N_;
    const f16* eefb  = eefh + (size_t)bh * N_ * N_;
    const f16* v1tb  = vt + (size_t)bh * 64 * N_;             // [d][n]
    const f16* v2tb  = vt + (size_t)(NBH + bh) * 64 * N_;     // [d][n]

    // ---- stage v2s[s][k] = v2t[dh*36+s][k] (ones for d>=64)
    {
#pragma unroll
        for (int rep = 0; rep < 7; ++rep) {
            const int idx = rep * 256 + tid;          // 36*48 = 1728 uint4 chunks
            if (idx < 1728) {
                const int s = idx / 48, c = idx - s * 48;
                const int d = dh * 36 + s;
                if (d < 64) {
                    *(uint4*)(v2s + s * 384 + c * 8) =
                        *(const uint4*)(v2tb + (size_t)d * N_ + c * 8);
                } else {
                    f16x8 one = {1, 1, 1, 1, 1, 1, 1, 1};
                    *(f16x8*)(v2s + s * 384 + c * 8) = one;
                }
            }
        }
    }

    // ---- register caches: eCD A-frags and eEF B-frags, full K=384
    f16x8 cf[4][12];
    f16x8 bf[4][12];
#pragma unroll
    for (int isub = 0; isub < 4; ++isub)
#pragma unroll
        for (int ks = 0; ks < 12; ++ks)
            cf[isub][ks] = *(const f16x8*)(ecdb + (size_t)(i0 + isub * 16 + lr) * N_ +
                                           ks * 32 + quad * 8);
#pragma unroll
    for (int js = 0; js < 4; ++js)
#pragma unroll
        for (int ks = 0; ks < 12; ++ks)
            bf[js][ks] = *(const f16x8*)(eefb + (size_t)(j0 + js * 16 + lr) * N_ +
                                         ks * 32 + quad * 8);
    __syncthreads();

    for (int t = 0; t < 9; ++t) {
        const int s  = w * 9 + t;
        const int dd = dh * 36 + s;
        if (dd > 64) break;               // wave-uniform (w,t only)

        f32x4 acc[4][4];
#pragma unroll
        for (int a = 0; a < 4; ++a)
#pragma unroll
            for (int b = 0; b < 4; ++b)
                acc[a][b] = (f32x4){0.f, 0.f, 0.f, 0.f};

#pragma unroll
        for (int ks = 0; ks < 12; ++ks) {
            const f16x8 v2f = *(const f16x8*)(v2s + s * 384 + ks * 32 + quad * 8);
            f16x8 af[4];
#pragma unroll
            for (int isub = 0; isub < 4; ++isub)
                af[isub] = cf[isub][ks] * v2f;        // v_pk_mul_f16 x4
#pragma unroll
            for (int js = 0; js < 4; ++js)
#pragma unroll
                for (int isub = 0; isub < 4; ++isub)
                    acc[isub][js] = __builtin_amdgcn_mfma_f32_16x16x32_f16(
                        af[isub], bf[js][ks], acc[isub][js], 0, 0, 0);
        }

        // ---- fold: numacc[i-frag] = sum_j eABt[j,i]*v1[j]*acc
        float numacc[16];
#pragma unroll
        for (int r = 0; r < 16; ++r) numacc[r] = 0.f;
#pragma unroll
        for (int js = 0; js < 4; ++js) {
            const float v1v = (dd < 64) ? (float)v1tb[(size_t)dd * N_ + j0 + js * 16 + lr]
                                        : 1.0f;
#pragma unroll
            for (int isub = 0; isub < 4; ++isub) {
                const f16x4 ab = *(const f16x4*)(eabtb + (size_t)(j0 + js * 16 + lr) * N_ +
                                                 i0 + isub * 16 + quad * 4);
#pragma unroll
                for (int q = 0; q < 4; ++q)
                    numacc[isub * 4 + q] += (float)ab[q] * (v1v * acc[isub][js][q]);
            }
        }
#pragma unroll
        for (int r = 0; r < 16; ++r) {
            float v = numacc[r];
            v += __shfl_xor(v, 1);
            v += __shfl_xor(v, 2);
            v += __shfl_xor(v, 4);
            v += __shfl_xor(v, 8);
            numacc[r] = v;
        }
        if (lr == 0) {
#pragma unroll
            for (int r = 0; r < 16; ++r) {
                const int i = i0 + (r >> 2) * 16 + quad * 4 + (r & 3);
                numw6[((size_t)(jt * NBH + bh) * N_ + i) * 68 + dd] = numacc[r];
            }
        }
    }
}

// ---------------------------------------------------------------------------
// Kernel 4: out = (sum_jt num) / (sum_jt den)
// ---------------------------------------------------------------------------
__global__ __launch_bounds__(256) void finalize_kernel(const float* __restrict__ numw6,
                                                       float* __restrict__ out) {
    const int o = blockIdx.x * 256 + threadIdx.x;
    const int b = o / (N_ * C_);
    const int rem = o - b * (N_ * C_);
    const int n = rem >> 8;
    const int cc = rem & 255;
    const int h = cc >> 6, d = cc & 63;
    const size_t base = (size_t)((b * H_ + h) * N_ + n) * 68;
    float num = 0.f, den = 0.f;
#pragma unroll
    for (int jt = 0; jt < 6; ++jt) {
        const float* p = numw6 + (size_t)jt * NBH * N_ * 68 + base;
        num += p[d];
        den += p[64];
    }
    out[o] = num / den;
}

extern "C" void kernel_launch(void* const* d_in, const int* in_sizes, int n_in,
                              void* d_out, int out_size, void* d_ws, size_t ws_size,
                              hipStream_t stream) {
    const float* x = (const float*)d_in[0];
    const float* W = (const float*)d_in[1];
    float* ws    = (float*)d_ws;
    float* proj  = ws;                               // 5*TSZ f32        (3.93 MB)
    float* numw6 = ws + 5 * TSZ;                     // 6*8*384*68 f32   (5.01 MB)
    f16*   eabt  = (f16*)(numw6 + 6 * NBH * N_ * 68);// ESZ f16          (2.36 MB)
    f16*   eefh  = eabt + ESZ;                       // ESZ f16
    f16*   ecdh  = eefh + ESZ;                       // ESZ f16
    f16*   vt    = ecdh + ESZ;                       // 2*8*64*384 f16   (0.79 MB)
    // total ~ 16.9 MB of d_ws

    proj_kernel<<<dim3(12, 20), 256, 0, stream>>>(x, W, proj);
    logits_kernel<<<dim3(6, 6, 24), 256, 0, stream>>>(proj, eabt, ecdh, eefh);
    vtrans_kernel<<<dim3(6, 8, 2), 256, 0, stream>>>(proj, vt);
    triplet_reg_kernel<<<dim3(6, 6, 16), 256, 0, stream>>>(eabt, ecdh, eefh, vt, numw6);
    finalize_kernel<<<dim3(768), 256, 0, stream>>>(numw6, (float*)d_out);
}